// Round 8
// baseline (221.385 us; speedup 1.0000x reference)
//
#include <hip/hip_runtime.h>

#define HIDDEN 128
#define SLOT_H 264
#define BSHIFT 10           // dst bucket = dst >> 10
#define NBMAX 128           // >= 98 buckets
#define CAP 11264           // slots/bucket: mean 10204, sigma ~100 -> +10 sigma headroom
#define OVF_MAX 65536

typedef _Float16 f16;
typedef f16 f16x2 __attribute__((ext_vector_type(2)));
typedef f16 f16x8 __attribute__((ext_vector_type(8)));
typedef float f32x4 __attribute__((ext_vector_type(4)));   // native vector: nontemporal-load OK
typedef float f32x16 __attribute__((ext_vector_type(16)));
typedef unsigned long long ull;

static __device__ __forceinline__ float fdot2(f16x2 a, f16x2 b, float c) {
    return __builtin_amdgcn_fdot2(a, b, c, false);   // v_dot2_f32_f16
}

// wsh_t[n][k] = Wsym[k][n]; also inits cursor[b]=b*CAP and ovf_cnt=0 (ws is re-poisoned)
__global__ __launch_bounds__(256) void prep_w(const float* __restrict__ w,
                                              f16* __restrict__ wsh_t,
                                              int* __restrict__ cursor,
                                              int* __restrict__ ovf_cnt) {
    int idx = blockIdx.x * 256 + threadIdx.x;   // 0..16383
    if (idx < NBMAX) cursor[idx] = idx * CAP;
    if (idx == NBMAX) ovf_cnt[0] = 0;
    int n = idx >> 7, k = idx & 127;
    wsh_t[idx] = (f16)(w[k * HIDDEN + n] + w[n * HIDDEN + k]);
}

// single-pass block-aggregated counting scatter into fixed-capacity buckets
// perm[pos] = src | dst<<17 | e<<34
__global__ __launch_bounds__(256) void scatter_k(const int* __restrict__ eidx,
                                                 int* __restrict__ cursor,
                                                 ull* __restrict__ perm,
                                                 ull* __restrict__ ovf,
                                                 int* __restrict__ ovf_cnt,
                                                 int E, int nb) {
    __shared__ int lh[NBMAX], lbase[NBMAX], lrank[NBMAX];
    int tid = threadIdx.x;
    int base = blockIdx.x * 4096;
    if (tid < NBMAX) { lh[tid] = 0; lrank[tid] = 0; }
    __syncthreads();
    int s[16], d[16], bb[16];
    #pragma unroll
    for (int i = 0; i < 16; ++i) {
        int e = base + i * 256 + tid;
        bb[i] = -1;
        if (e < E) {
            s[i] = eidx[e]; d[i] = eidx[E + e];
            bb[i] = d[i] >> BSHIFT;
            atomicAdd(&lh[bb[i]], 1);
        }
    }
    __syncthreads();
    if (tid < nb && lh[tid]) lbase[tid] = atomicAdd(&cursor[tid], lh[tid]);
    __syncthreads();
    #pragma unroll
    for (int i = 0; i < 16; ++i) {
        if (bb[i] >= 0) {
            int e = base + i * 256 + tid;
            int r = atomicAdd(&lrank[bb[i]], 1);
            long pos = (long)lbase[bb[i]] + r;
            ull v = (ull)s[i] | ((ull)d[i] << 17) | ((ull)e << 34);
            if (pos < (long)(bb[i] + 1) * CAP) perm[pos] = v;
            else {                                   // statistically ~never
                int o = atomicAdd(ovf_cnt, 1);
                if (o < OVF_MAX) ovf[o] = v;
            }
        }
    }
}

// uh = (f16)(z @ Wsym), zh = (f16)z — fused MFMA 32x32x16_f16 (measured-good since R5)
__global__ __launch_bounds__(256, 3) void gemm_mfma2(const float* __restrict__ z,
                                                     const f16* __restrict__ wsh_t,
                                                     f16* __restrict__ zh,
                                                     f16* __restrict__ uh, int nrows) {
    __shared__ f16 afrag[64 * SLOT_H];
    int tid = threadIdx.x;
    int row0 = blockIdx.x * 128;
    if (row0 > nrows - 128) row0 = nrows - 128;

    {
        const float4* zg = (const float4*)(z + (size_t)row0 * HIDDEN);
        f16x8* zhg = (f16x8*)(zh + (size_t)row0 * HIDDEN);
        #pragma unroll
        for (int it = 0; it < 8; ++it) {
            int g = it * 256 + tid;
            float4 v0 = zg[2 * g];
            float4 v1 = zg[2 * g + 1];
            f16x8 h = {(f16)v0.x, (f16)v0.y, (f16)v0.z, (f16)v0.w,
                       (f16)v1.x, (f16)v1.y, (f16)v1.z, (f16)v1.w};
            zhg[g] = h;
            int row = g >> 4, ch = g & 15;
            int slot = (row >> 5) * 16 + ch;
            *(f16x8*)&afrag[slot * SLOT_H + (row & 31) * 8] = h;
        }
    }
    __syncthreads();

    int wave = tid >> 6, lane = tid & 63;
    int m = lane & 31, half = lane >> 5;
    const f16* wb = wsh_t + (size_t)m * HIDDEN + half * 8;

    f32x16 acc0, acc1, acc2, acc3;
    #pragma unroll
    for (int r = 0; r < 16; ++r) { acc0[r] = 0.f; acc1[r] = 0.f; acc2[r] = 0.f; acc3[r] = 0.f; }

    #pragma unroll
    for (int ks = 0; ks < 8; ++ks) {
        f16x8 a = *(const f16x8*)&afrag[(wave * 16 + ks * 2 + half) * SLOT_H + m * 8];
        f16x8 b0 = *(const f16x8*)&wb[ 0 * HIDDEN + 16 * ks];
        f16x8 b1 = *(const f16x8*)&wb[32 * HIDDEN + 16 * ks];
        f16x8 b2 = *(const f16x8*)&wb[64 * HIDDEN + 16 * ks];
        f16x8 b3 = *(const f16x8*)&wb[96 * HIDDEN + 16 * ks];
        acc0 = __builtin_amdgcn_mfma_f32_32x32x16_f16(a, b0, acc0, 0, 0, 0);
        acc1 = __builtin_amdgcn_mfma_f32_32x32x16_f16(a, b1, acc1, 0, 0, 0);
        acc2 = __builtin_amdgcn_mfma_f32_32x32x16_f16(a, b2, acc2, 0, 0, 0);
        acc3 = __builtin_amdgcn_mfma_f32_32x32x16_f16(a, b3, acc3, 0, 0, 0);
    }

    f16* ur = uh + (size_t)(row0 + wave * 32) * HIDDEN;
    #pragma unroll
    for (int r = 0; r < 16; ++r) {
        int row = (r & 3) + 8 * (r >> 2) + 4 * half;
        f16* p = ur + (size_t)row * HIDDEN + m;
        p[0]  = (f16)acc0[r];
        p[32] = (f16)acc1[r];
        p[64] = (f16)acc2[r];
        p[96] = (f16)acc3[r];
    }
}

static __device__ __forceinline__ void score_edge(const f16* uh, const f16* zh,
                                                  ull p, float* out, int t) {
    int src = (int)(p & 0x1FFFF);
    int dst = (int)((p >> 17) & 0x1FFFF);
    int eid = (int)(p >> 34);
    const f32x4* a4 = (const f32x4*)(uh + (size_t)src * HIDDEN);
    const f32x4* b4 = (const f32x4*)(zh + (size_t)dst * HIDDEN);
    f32x4 av = __builtin_nontemporal_load(&a4[t]);   // random src: don't pollute L2
    f32x4 bv = b4[t];                                // binned dst: keep in L2
    const f16x2* ap = (const f16x2*)&av;
    const f16x2* bp = (const f16x2*)&bv;
    float s = 0.f;
    #pragma unroll
    for (int i = 0; i < 4; ++i) s = fdot2(ap[i], bp[i], s);
    #pragma unroll
    for (int off = 8; off > 0; off >>= 1) s += __shfl_down(s, off, 16);
    if (t == 0) out[eid] = 1.0f / (1.0f + __expf(-s));
}

// binned scoring over slotted perm; slack slots skipped via cursor check
__global__ __launch_bounds__(256) void edge_bin(const f16* __restrict__ uh,
                                                const f16* __restrict__ zh,
                                                const ull* __restrict__ perm,
                                                const int* __restrict__ cursor,
                                                float* __restrict__ out, int cpx) {
    int tid = threadIdx.x;
    int g = tid >> 4, t = tid & 15;
    int b = blockIdx.x;
    int chunk = (b & 7) * cpx + (b >> 3);     // XCD b%8 -> contiguous slice (~3.1 MB dst, fits L2)
    long slot = (long)chunk * 16 + g;
    int bk = (int)(slot / CAP);
    int end = cursor[bk];                     // bk*CAP + count (hot 4 B, wave-coherent)
    int lim = (bk + 1) * CAP;
    if (slot >= (end < lim ? end : lim)) return;
    score_edge(uh, zh, perm[slot], out, t);
}

// overflow edges (statistically none): fixed grid, count read device-side
__global__ __launch_bounds__(256) void edge_ovf(const f16* __restrict__ uh,
                                                const f16* __restrict__ zh,
                                                const ull* __restrict__ ovf,
                                                const int* __restrict__ ovf_cnt,
                                                float* __restrict__ out) {
    int n = ovf_cnt[0];
    if (n > OVF_MAX) n = OVF_MAX;
    int tid = threadIdx.x;
    int g = tid >> 4, t = tid & 15;
    for (int i = blockIdx.x * 16 + g; i < n; i += gridDim.x * 16)
        score_edge(uh, zh, ovf[i], out, t);
}

// fallback (R5 path) if workspace too small for the binned layout
__global__ __launch_bounds__(256) void edge_score16(const f16* __restrict__ uh,
                                                    const f16* __restrict__ zh,
                                                    const int* __restrict__ eidx,
                                                    float* __restrict__ out, int E) {
    int tid = threadIdx.x;
    int g = tid >> 4, t = tid & 15;
    int e = blockIdx.x * 16 + g;
    if (e >= E) return;
    ull p = (ull)eidx[e] | ((ull)eidx[E + e] << 17) | ((ull)e << 34);
    score_edge(uh, zh, p, out, t);
}

extern "C" void kernel_launch(void* const* d_in, const int* in_sizes, int n_in,
                              void* d_out, int out_size, void* d_ws, size_t ws_size,
                              hipStream_t stream) {
    const float* z    = (const float*)d_in[0];
    const int*   eidx = (const int*)d_in[1];
    const float* w    = (const float*)d_in[2];
    float* out = (float*)d_out;

    int nrows = in_sizes[0] / HIDDEN;   // 100000
    int E = out_size;                    // 1000000
    int nb = (nrows >> BSHIFT) + 1;      // 98

    f16* wsh_t  = (f16*)d_ws;                               // 32 KB
    f16* zh     = wsh_t + HIDDEN * HIDDEN;                  // 25.6 MB
    f16* uh     = zh + (size_t)nrows * HIDDEN;              // 25.6 MB
    int* cursor = (int*)(uh + (size_t)nrows * HIDDEN);      // NBMAX ints (8B-aligned)
    int* ovf_cnt = cursor + NBMAX;                          // 2 ints (pad to 8B)
    ull* ovf    = (ull*)(ovf_cnt + 2);                      // 512 KB
    ull* perm   = ovf + OVF_MAX;                            // nb*CAP slots

    long nslots = (long)nb * CAP;
    size_t need = (size_t)((char*)(perm + nslots) - (char*)d_ws);
    bool binned = ws_size >= need;       // ws_size fixed per session -> same path every call

    prep_w<<<64, 256, 0, stream>>>(w, wsh_t, cursor, ovf_cnt);
    if (binned)
        scatter_k<<<(E + 4095) / 4096, 256, 0, stream>>>(eidx, cursor, perm, ovf, ovf_cnt, E, nb);
    gemm_mfma2<<<(nrows + 127) / 128, 256, 0, stream>>>(z, wsh_t, zh, uh, nrows);
    if (binned) {
        long nch = (nslots + 15) / 16;
        int cpx = (int)((nch + 7) / 8);
        edge_bin<<<8 * cpx, 256, 0, stream>>>(uh, zh, perm, cursor, out, cpx);
        edge_ovf<<<32, 256, 0, stream>>>(uh, zh, ovf, ovf_cnt, out);
    } else {
        edge_score16<<<(E + 15) / 16, 256, 0, stream>>>(uh, zh, eidx, out, E);
    }
}

// Round 9
// 165.858 us; speedup vs baseline: 1.3348x; 1.3348x over previous
//
#include <hip/hip_runtime.h>

#define HIDDEN 128
#define LDSW 136            // halves; 272 B row stride, conflict-free b128 (0 conflicts measured)
#define BSHIFT 10           // dst bucket = dst >> 10
#define NBMAX 128           // >= 98 buckets
#define CAP 10752           // slots/bucket: mean 10240, sigma ~101 -> +5 sigma; overflow path covers rest
#define OVF_MAX 65536

typedef _Float16 f16;
typedef f16 f16x2 __attribute__((ext_vector_type(2)));
typedef f16 f16x8 __attribute__((ext_vector_type(8)));
typedef float f32x16 __attribute__((ext_vector_type(16)));
typedef unsigned long long ull;

static __device__ __forceinline__ float fdot2(f16x2 a, f16x2 b, float c) {
    return __builtin_amdgcn_fdot2(a, b, c, false);   // v_dot2_f32_f16
}

// wsh_t[n][k] = Wsym[k][n] (fp16, B-operand layout); init cursor[b]=b*CAP, ovf_cnt=0
__global__ __launch_bounds__(256) void prep_w(const float* __restrict__ w,
                                              f16* __restrict__ wsh_t,
                                              int* __restrict__ cursor,
                                              int* __restrict__ ovf_cnt) {
    int idx = blockIdx.x * 256 + threadIdx.x;   // 0..16383
    if (idx < NBMAX) cursor[idx] = idx * CAP;
    if (idx == NBMAX) ovf_cnt[0] = 0;
    int n = idx >> 7, k = idx & 127;
    wsh_t[idx] = (f16)(w[k * HIDDEN + n] + w[n * HIDDEN + k]);
}

// Fused launch: blocks [0,ngemm) = MFMA gemm tiles (R4 body, measured 19 µs);
// blocks [ngemm, ...) = fixed-capacity counting scatter (independent work, hides in gemm).
__global__ __launch_bounds__(256) void gemm_scatter(const float* __restrict__ z,
                                                    const f16* __restrict__ wsh_t,
                                                    f16* __restrict__ zh,
                                                    f16* __restrict__ uh,
                                                    const int* __restrict__ eidx,
                                                    int* __restrict__ cursor,
                                                    ull* __restrict__ perm,
                                                    ull* __restrict__ ovf,
                                                    int* __restrict__ ovf_cnt,
                                                    int nrows, int E, int nb, int ngemm) {
    __shared__ f16 wlt[HIDDEN * LDSW];   // 34816 B (gemm); scatter overlays 1.5 KB of it
    int tid = threadIdx.x;

    if (blockIdx.x >= ngemm) {
        // ---- scatter path: perm[pos] = src | dst<<17 | e<<34 ----
        int* lh    = (int*)wlt;
        int* lbase = lh + NBMAX;
        int* lrank = lbase + NBMAX;
        int base = (blockIdx.x - ngemm) * 4096;
        if (tid < NBMAX) { lh[tid] = 0; lrank[tid] = 0; }
        __syncthreads();
        int s[16], d[16], bb[16];
        #pragma unroll
        for (int i = 0; i < 16; ++i) {
            int e = base + i * 256 + tid;
            bb[i] = -1;
            if (e < E) {
                s[i] = eidx[e]; d[i] = eidx[E + e];
                bb[i] = d[i] >> BSHIFT;
                atomicAdd(&lh[bb[i]], 1);
            }
        }
        __syncthreads();
        if (tid < nb && lh[tid]) lbase[tid] = atomicAdd(&cursor[tid], lh[tid]);
        __syncthreads();
        #pragma unroll
        for (int i = 0; i < 16; ++i) {
            if (bb[i] >= 0) {
                int e = base + i * 256 + tid;
                int r = atomicAdd(&lrank[bb[i]], 1);
                long pos = (long)lbase[bb[i]] + r;
                ull v = (ull)s[i] | ((ull)d[i] << 17) | ((ull)e << 34);
                if (pos < (long)(bb[i] + 1) * CAP) perm[pos] = v;
                else {                                   // statistically ~never
                    int o = atomicAdd(ovf_cnt, 1);
                    if (o < OVF_MAX) ovf[o] = v;
                }
            }
        }
        return;
    }

    // ---- gemm path (R4 body): uh = (f16)(z @ Wsym), zh = (f16)z fused ----
    {   // stage W^T: 2048 16B chunks, coalesced
        const f16x8* g = (const f16x8*)wsh_t;
        #pragma unroll
        for (int it = 0; it < 8; ++it) {
            int idx = it * 256 + tid;
            int j = idx >> 4, kc = idx & 15;
            *(f16x8*)&wlt[j * LDSW + kc * 8] = g[idx];
        }
    }
    __syncthreads();

    int wave = tid >> 6, lane = tid & 63;
    int row0 = blockIdx.x * 128 + wave * 32;
    if (row0 > nrows - 32) row0 = nrows - 32;   // tail overlap: identical writes, benign

    int m = lane & 31, half = lane >> 5;        // A: row=m, k=half*8+j
    const float* zr = z  + (size_t)(row0 + m) * HIDDEN + half * 8;
    f16*        zhr = zh + (size_t)(row0 + m) * HIDDEN + half * 8;
    const f16* wbase = &wlt[m * LDSW + half * 8];

    f32x16 acc0, acc1, acc2, acc3;
    #pragma unroll
    for (int r = 0; r < 16; ++r) { acc0[r] = 0.f; acc1[r] = 0.f; acc2[r] = 0.f; acc3[r] = 0.f; }

    #pragma unroll
    for (int ks = 0; ks < 8; ++ks) {            // K = 16 per step
        float4 a0 = *(const float4*)(zr + 16 * ks);
        float4 a1 = *(const float4*)(zr + 16 * ks + 4);
        f16x8 af = {(f16)a0.x, (f16)a0.y, (f16)a0.z, (f16)a0.w,
                    (f16)a1.x, (f16)a1.y, (f16)a1.z, (f16)a1.w};
        *(f16x8*)(zhr + 16 * ks) = af;          // fused zh emit
        f16x8 b0 = *(const f16x8*)(wbase + 16 * ks);
        f16x8 b1 = *(const f16x8*)(wbase + 32 * LDSW + 16 * ks);
        f16x8 b2 = *(const f16x8*)(wbase + 64 * LDSW + 16 * ks);
        f16x8 b3 = *(const f16x8*)(wbase + 96 * LDSW + 16 * ks);
        acc0 = __builtin_amdgcn_mfma_f32_32x32x16_f16(af, b0, acc0, 0, 0, 0);
        acc1 = __builtin_amdgcn_mfma_f32_32x32x16_f16(af, b1, acc1, 0, 0, 0);
        acc2 = __builtin_amdgcn_mfma_f32_32x32x16_f16(af, b2, acc2, 0, 0, 0);
        acc3 = __builtin_amdgcn_mfma_f32_32x32x16_f16(af, b3, acc3, 0, 0, 0);
    }

    // C/D: col = m (+32/tile), row = (r&3) + 8*(r>>2) + 4*half   [m74/m101]
    f16* ur = uh + (size_t)row0 * HIDDEN;
    #pragma unroll
    for (int r = 0; r < 16; ++r) {
        int row = (r & 3) + 8 * (r >> 2) + 4 * half;
        f16* p = ur + (size_t)row * HIDDEN + m;
        p[0]  = (f16)acc0[r];
        p[32] = (f16)acc1[r];
        p[64] = (f16)acc2[r];
        p[96] = (f16)acc3[r];
    }
}

// Gathers unconditional (slack slots decode to safe in-workspace rows); store predicated.
static __device__ __forceinline__ void score_edge(const f16* uh, const f16* zh,
                                                  ull p, float* out, int t, int E) {
    int src = (int)(p & 0x1FFFF);
    int dst = (int)((p >> 17) & 0x1FFFF);
    int eid = (int)(p >> 34);
    const float4* a4 = (const float4*)(uh + (size_t)src * HIDDEN);
    const float4* b4 = (const float4*)(zh + (size_t)dst * HIDDEN);
    float4 av = a4[t], bv = b4[t];   // plain loads: src reuse (~10x) wants caching
    const f16x2* ap = (const f16x2*)&av;
    const f16x2* bp = (const f16x2*)&bv;
    float s = 0.f;
    #pragma unroll
    for (int i = 0; i < 4; ++i) s = fdot2(ap[i], bp[i], s);
    #pragma unroll
    for (int off = 8; off > 0; off >>= 1) s += __shfl_down(s, off, 16);
    if (t == 0 && eid < E) out[eid] = 1.0f / (1.0f + __expf(-s));
}

// Binned scoring over slotted perm (XCD-swizzled) + overflow tail blocks fused.
__global__ __launch_bounds__(256) void edge_bin(const f16* __restrict__ uh,
                                                const f16* __restrict__ zh,
                                                const ull* __restrict__ perm,
                                                const ull* __restrict__ ovf,
                                                const int* __restrict__ ovf_cnt,
                                                float* __restrict__ out,
                                                int E, int cpx, int nmain) {
    int tid = threadIdx.x;
    int g = tid >> 4, t = tid & 15;
    int b = blockIdx.x;
    if (b >= nmain) {                         // overflow tail (statistically empty)
        int n = ovf_cnt[0];
        if (n > OVF_MAX) n = OVF_MAX;
        for (int i = (b - nmain) * 16 + g; i < n; i += 32 * 16)
            score_edge(uh, zh, ovf[i], out, t, E);
        return;
    }
    int chunk = (b & 7) * cpx + (b >> 3);     // XCD b%8 -> contiguous ~3 MB dst slice (fits L2)
    long slot = (long)chunk * 16 + g;
    score_edge(uh, zh, perm[slot], out, t, E);
}

// fallback (R5 path) if workspace too small for the binned layout
__global__ __launch_bounds__(256) void edge_score16(const f16* __restrict__ uh,
                                                    const f16* __restrict__ zh,
                                                    const int* __restrict__ eidx,
                                                    float* __restrict__ out, int E) {
    int tid = threadIdx.x;
    int g = tid >> 4, t = tid & 15;
    int e = blockIdx.x * 16 + g;
    if (e >= E) return;
    ull p = (ull)eidx[e] | ((ull)eidx[E + e] << 17) | ((ull)e << 34);
    score_edge(uh, zh, p, out, t, E);
}

extern "C" void kernel_launch(void* const* d_in, const int* in_sizes, int n_in,
                              void* d_out, int out_size, void* d_ws, size_t ws_size,
                              hipStream_t stream) {
    const float* z    = (const float*)d_in[0];
    const int*   eidx = (const int*)d_in[1];
    const float* w    = (const float*)d_in[2];
    float* out = (float*)d_out;

    int nrows = in_sizes[0] / HIDDEN;   // 100000
    int E = out_size;                    // 1000000
    int nb = (nrows >> BSHIFT) + 1;      // 98

    f16* wsh_t  = (f16*)d_ws;                               // 32 KB
    f16* zh     = wsh_t + HIDDEN * HIDDEN;                  // 25.6 MB
    f16* uh     = zh + (size_t)nrows * HIDDEN;              // 25.6 MB
    int* cursor = (int*)(uh + (size_t)nrows * HIDDEN);      // NBMAX ints
    int* ovf_cnt = cursor + NBMAX;                          // 2 ints
    ull* ovf    = (ull*)(ovf_cnt + 2);                      // 512 KB
    ull* perm   = ovf + OVF_MAX;                            // nb*CAP slots (~8.4 MB)

    long nslots = (long)nb * CAP;
    size_t need = (size_t)((char*)(perm + nslots) - (char*)d_ws);
    bool binned = ws_size >= need;       // ws_size fixed per session -> same path every call

    int ngemm = (nrows + 127) / 128;     // 782
    int nscat = (E + 4095) / 4096;       // 245

    prep_w<<<64, 256, 0, stream>>>(w, wsh_t, cursor, ovf_cnt);
    if (binned) {
        gemm_scatter<<<ngemm + nscat, 256, 0, stream>>>(z, wsh_t, zh, uh, eidx, cursor,
                                                        perm, ovf, ovf_cnt, nrows, E, nb, ngemm);
        long ngrp = nslots / 16;          // 98*10752/16 = 65856, divisible by 8
        int cpx = (int)(ngrp / 8);
        int nmain = (int)ngrp;
        edge_bin<<<nmain + 32, 256, 0, stream>>>(uh, zh, perm, ovf, ovf_cnt, out, E, cpx, nmain);
    } else {
        gemm_scatter<<<ngemm, 256, 0, stream>>>(z, wsh_t, zh, uh, eidx, cursor,
                                                perm, ovf, ovf_cnt, nrows, E, nb, ngemm);
        edge_score16<<<(E + 15) / 16, 256, 0, stream>>>(uh, zh, eidx, out, E);
    }
}